// Round 3
// baseline (329.008 us; speedup 1.0000x reference)
//
#include <hip/hip_runtime.h>
#include <hip/hip_bf16.h>
#include <math.h>

typedef __hip_bfloat16 bf16;
typedef __attribute__((ext_vector_type(8))) short bf16x8;
typedef __attribute__((ext_vector_type(4))) float f32x4;

// ---------------- dtype-flexible accessors ----------------
__device__ __forceinline__ float loadf(const void* p, size_t i, bool f32m) {
    return f32m ? ((const float*)p)[i]
                : __bfloat162float(((const bf16*)p)[i]);
}
__device__ __forceinline__ void storef(void* p, size_t i, float v, bool f32m) {
    if (f32m) ((float*)p)[i] = v;
    else      ((bf16*)p)[i] = __float2bfloat16(v);
}
// row 0 = src, row 1 = dst; e64 => int64 buffer, read low word
__device__ __forceinline__ int ldidx(const int* w, size_t e, bool e64, size_t E, int row) {
    return e64 ? w[2 * (row * E + e)] : w[row * E + e];
}

// ---------------- dtype detection (one wave) ----------------
__global__ void k_detect(const void* x, const int* ei, float* flags) {
    int lane = threadIdx.x;
    const unsigned short* hx = (const unsigned short*)x;
    unsigned short u = hx[2 * lane];
    int ex = (u >> 7) & 0xFF;
    bool tame = (ex >= 117 && ex <= 136);
    unsigned long long mt = __ballot(tame);
    unsigned long long mz = __ballot(ei[2 * lane + 1] != 0);
    if (lane == 0) {
        flags[0] = (__popcll(mt) >= 48) ? 0.0f : 1.0f;  // 1 => f32 inputs
        flags[1] = (mz == 0ULL) ? 1.0f : 0.0f;          // 1 => int64 edge_index
    }
}

// ---------------- CSR build: 2-level counting sort ----------------
// bucket = dst >> 8 (256 nodes per bucket), NB = ceil(n/256) <= 512

__global__ void k_zero_small(int* __restrict__ p, int m) {
    int i = blockIdx.x * 256 + threadIdx.x;
    if (i < m) p[i] = 0;
}

#define SCB_EPT 16   // edges per thread in hist/scatter (4096 per block)

__global__ __launch_bounds__(256) void k_bucket_hist(const int* __restrict__ ei,
                                                     const float* __restrict__ flags,
                                                     int* __restrict__ bcnt, int E, int NB) {
    __shared__ int lcnt[512];
    bool e64 = flags[1] > 0.5f;
    int tid = threadIdx.x;
    for (int i = tid; i < NB; i += 256) lcnt[i] = 0;
    __syncthreads();
    int base = blockIdx.x * 256 * SCB_EPT;
#pragma unroll
    for (int j = 0; j < SCB_EPT; ++j) {
        int e = base + j * 256 + tid;
        if (e < E) atomicAdd(&lcnt[ldidx(ei, e, e64, E, 1) >> 8], 1);
    }
    __syncthreads();
    for (int i = tid; i < NB; i += 256) {
        int c = lcnt[i];
        if (c) atomicAdd(&bcnt[i], c);
    }
}

// single block of 512: scan bcnt -> bbase (exclusive, NB+1), bcur copy
__global__ __launch_bounds__(512) void k_scan_buckets(const int* __restrict__ bcnt,
                                                      int* __restrict__ bbase,
                                                      int* __restrict__ bcur, int NB) {
    __shared__ int sh[512];
    int tid = threadIdx.x;
    int v = (tid < NB) ? bcnt[tid] : 0;
    sh[tid] = v;
    __syncthreads();
    for (int off = 1; off < 512; off <<= 1) {
        int t = (tid >= off) ? sh[tid - off] : 0;
        __syncthreads();
        sh[tid] += t;
        __syncthreads();
    }
    if (tid < NB) {
        int ex = sh[tid] - v;
        bbase[tid] = ex;
        bcur[tid] = ex;
    }
    if (tid == 0) bbase[NB] = sh[511];
}

// scatter (src,dst) records into bucket regions; per-block LDS rank ->
// consecutive positions per (block,bucket) -> near-sequential writes
__global__ __launch_bounds__(256) void k_bucket_scatter(const int* __restrict__ ei,
                                                        const float* __restrict__ flags,
                                                        int* __restrict__ bcur,
                                                        int2* __restrict__ recs,
                                                        int E, int NB) {
    __shared__ int lcnt[512], lrank[512], lbase[512];
    bool e64 = flags[1] > 0.5f;
    int tid = threadIdx.x;
    for (int i = tid; i < NB; i += 256) { lcnt[i] = 0; lrank[i] = 0; }
    __syncthreads();
    int base = blockIdx.x * 256 * SCB_EPT;
    int s[SCB_EPT], d[SCB_EPT];
#pragma unroll
    for (int j = 0; j < SCB_EPT; ++j) {
        int e = base + j * 256 + tid;
        if (e < E) {
            s[j] = ldidx(ei, e, e64, E, 0);
            d[j] = ldidx(ei, e, e64, E, 1);
            atomicAdd(&lcnt[d[j] >> 8], 1);
        } else d[j] = -1;
    }
    __syncthreads();
    for (int i = tid; i < NB; i += 256) {
        int c = lcnt[i];
        lbase[i] = c ? atomicAdd(&bcur[i], c) : 0;
    }
    __syncthreads();
#pragma unroll
    for (int j = 0; j < SCB_EPT; ++j) {
        if (d[j] >= 0) {
            int b = d[j] >> 8;
            int r = atomicAdd(&lrank[b], 1);
            recs[lbase[b] + r] = make_int2(s[j], d[j]);
        }
    }
}

// one block per bucket: node counts + scan -> rowptr, dinv; then scatter srcs
// into the bucket's contiguous range (L2-local full-line writes)
__global__ __launch_bounds__(256) void k_bucket_csr(const int2* __restrict__ recs,
                                                    const int* __restrict__ bbase,
                                                    int* __restrict__ rowptr,
                                                    float* __restrict__ dinv,
                                                    int* __restrict__ srcs,
                                                    int n, int E) {
    __shared__ int lcnt[256];
    __shared__ int lcur[256];
    int b = blockIdx.x, tid = threadIdx.x;
    int e0 = bbase[b], e1 = bbase[b + 1];
    lcnt[tid] = 0;
    __syncthreads();
    for (int i = e0 + tid; i < e1; i += 256)
        atomicAdd(&lcnt[recs[i].y & 255], 1);
    __syncthreads();
    int c = lcnt[tid];
    lcur[tid] = c;
    __syncthreads();
    for (int off = 1; off < 256; off <<= 1) {
        int t = (tid >= off) ? lcur[tid - off] : 0;
        __syncthreads();
        lcur[tid] += t;
        __syncthreads();
    }
    int rp = bbase[b] + lcur[tid] - c;   // exclusive
    int node = (b << 8) + tid;
    if (node < n) {
        rowptr[node] = rp;
        dinv[node] = rsqrtf((float)(c + 1));
    }
    lcur[tid] = rp;
    __syncthreads();
    for (int i = e0 + tid; i < e1; i += 256) {
        int2 r = recs[i];
        int pos = atomicAdd(&lcur[r.y & 255], 1);
        srcs[pos] = r.x;
    }
    if (b == 0 && tid == 0) rowptr[n] = E;
}

// ---------------- MFMA dense transform (bf16 mode): A = (X @ W1)*dinv ----------------
// X[N,128] bf16, W[128,64] bf16. 4 waves/block, 64 rows x 64 cols per block.
// A-fragments straight from global (lane m=lane&15 row, k=(lane>>4)*8);
// W^T staged in LDS [64][136] bf16 (pad 136 -> 2-way banks = free).
__global__ __launch_bounds__(256) void k_gemm_mfma1(const void* __restrict__ X,
                                                    const void* __restrict__ W,
                                                    const float* __restrict__ flags,
                                                    const float* __restrict__ rowscale,
                                                    float* __restrict__ out, int n) {
    if (flags[0] > 0.5f) return;   // f32 mode handled by VALU kernel
    __shared__ __align__(16) unsigned short wl[64 * 136];   // wl[c][k] = W[k][c]
    int tid = threadIdx.x;
    const unsigned short* Wu = (const unsigned short*)W;
    for (int i = tid * 4; i < 128 * 64; i += 1024) {
        int k = i >> 6, c = i & 63;
        ushort4 v = *(const ushort4*)(Wu + i);
        wl[(c + 0) * 136 + k] = v.x;
        wl[(c + 1) * 136 + k] = v.y;
        wl[(c + 2) * 136 + k] = v.z;
        wl[(c + 3) * 136 + k] = v.w;
    }
    __syncthreads();

    int lane = tid & 63, wv = tid >> 6;
    int r0 = blockIdx.x * 64 + wv * 16;
    int mrow = lane & 15, kgrp = lane >> 4;
    int row = r0 + mrow;
    bool rok = (row < n);

    f32x4 acc[4];
#pragma unroll
    for (int ct = 0; ct < 4; ++ct) acc[ct] = (f32x4){0.0f, 0.0f, 0.0f, 0.0f};

    const unsigned short* xrow = (const unsigned short*)X + (size_t)(rok ? row : 0) * 128;

#pragma unroll
    for (int ks = 0; ks < 4; ++ks) {
        bf16x8 afrag = {0, 0, 0, 0, 0, 0, 0, 0};
        if (rok) afrag = *(const bf16x8*)(xrow + ks * 32 + kgrp * 8);
#pragma unroll
        for (int ct = 0; ct < 4; ++ct) {
            int c = ct * 16 + mrow;
            bf16x8 bfrag = *(const bf16x8*)&wl[c * 136 + ks * 32 + kgrp * 8];
            acc[ct] = __builtin_amdgcn_mfma_f32_16x16x32_bf16(afrag, bfrag, acc[ct], 0, 0, 0);
        }
    }

    // C/D: col = ct*16 + (lane&15), row(within tile) = kgrp*4 + reg
    float sc[4];
    int obase = r0 + kgrp * 4;
#pragma unroll
    for (int r = 0; r < 4; ++r)
        sc[r] = (obase + r < n) ? rowscale[obase + r] : 0.0f;
#pragma unroll
    for (int ct = 0; ct < 4; ++ct) {
#pragma unroll
        for (int r = 0; r < 4; ++r) {
            int orow = obase + r;
            if (orow < n)
                out[(size_t)orow * 64 + ct * 16 + mrow] = acc[ct][r] * sc[r];
        }
    }
}

// ---------------- dense transform: out[N,64] = (X[N,K] @ W[K,64]) * rowscale ----------------
// 64 rows/block, X tile + W fully in LDS, 4x4 register tile per thread.
// F32ONLY: early-exit unless f32 mode (bf16 mode handled by MFMA kernel).
template <int K, bool XF32, bool F32ONLY>
__global__ __launch_bounds__(256) void k_gemm3(const void* __restrict__ Xa,
                                               const void* __restrict__ Xb,
                                               const void* __restrict__ W,
                                               const float* __restrict__ flags,
                                               const float* __restrict__ rowscale,
                                               float* __restrict__ out, int n) {
    __shared__ float xs[64 * (K + 4)];
    __shared__ float wl[K * 68];
    bool f32m = flags[0] > 0.5f;
    if (F32ONLY && !f32m) return;
    const void* X = f32m ? Xa : Xb;
    bool xf32 = XF32 || f32m;
    int tid = threadIdx.x;
    int r0 = blockIdx.x * 64;

    if (f32m) {
        for (int i = tid * 4; i < K * 64; i += 1024) {
            int k = i >> 6, cc = i & 63;
            float4 v = *(const float4*)((const float*)W + i);
            *(float4*)&wl[k * 68 + cc] = v;
        }
    } else {
        for (int i = tid; i < K * 64; i += 256) {
            int k = i >> 6, cc = i & 63;
            wl[k * 68 + cc] = __bfloat162float(((const bf16*)W)[i]);
        }
    }
    if (xf32) {
        for (int i = tid * 4; i < 64 * K; i += 1024) {
            int row = i / K, k = i % K;
            float4 v = {0, 0, 0, 0};
            if (r0 + row < n) v = *(const float4*)((const float*)X + (size_t)(r0 + row) * K + k);
            *(float4*)&xs[row * (K + 4) + k] = v;
        }
    } else {
        for (int i = tid * 4; i < 64 * K; i += 1024) {
            int row = i / K, k = i % K;
            float4 v = {0, 0, 0, 0};
            if (r0 + row < n) {
                const bf16* p = (const bf16*)X + (size_t)(r0 + row) * K + k;
                v.x = __bfloat162float(p[0]); v.y = __bfloat162float(p[1]);
                v.z = __bfloat162float(p[2]); v.w = __bfloat162float(p[3]);
            }
            *(float4*)&xs[row * (K + 4) + k] = v;
        }
    }
    __syncthreads();

    int lane = tid & 63, wv = tid >> 6;
    int rg = lane >> 4, cg = lane & 15;
    int rbase = wv * 16 + rg * 4;
    int cbase = cg * 4;

    float acc[4][4];
#pragma unroll
    for (int r = 0; r < 4; ++r)
#pragma unroll
        for (int c = 0; c < 4; ++c) acc[r][c] = 0.0f;

#pragma unroll 2
    for (int k = 0; k < K; k += 4) {
        float4 xrv[4], wv4[4];
#pragma unroll
        for (int r = 0; r < 4; ++r)
            xrv[r] = *(const float4*)&xs[(rbase + r) * (K + 4) + k];
#pragma unroll
        for (int j = 0; j < 4; ++j)
            wv4[j] = *(const float4*)&wl[(k + j) * 68 + cbase];
#pragma unroll
        for (int r = 0; r < 4; ++r) {
            const float* xp = (const float*)&xrv[r];
#pragma unroll
            for (int j = 0; j < 4; ++j) {
                float xv = xp[j];
                acc[r][0] += xv * wv4[j].x;
                acc[r][1] += xv * wv4[j].y;
                acc[r][2] += xv * wv4[j].z;
                acc[r][3] += xv * wv4[j].w;
            }
        }
    }

#pragma unroll
    for (int r = 0; r < 4; ++r) {
        int row = r0 + rbase + r;
        if (row < n) {
            float sc = rowscale[row];
            float4 st = {acc[r][0] * sc, acc[r][1] * sc, acc[r][2] * sc, acc[r][3] * sc};
            *(float4*)&out[(size_t)row * 64 + cbase] = st;
        }
    }
}

// ---------------- fused aggregation: 2 nodes per wave, dwordx4 gathers ----------------
// t = A_scaled (rows pre-multiplied by dinv[src]); result = dv*(t[v] + sum t[s]) + bias
template <int EP>
__global__ __launch_bounds__(256) void k_agg(const float* __restrict__ t,
                                             const float* __restrict__ dinv,
                                             const int* __restrict__ rowptr,
                                             const int* __restrict__ srcs,
                                             const void* __restrict__ bias,
                                             const float* __restrict__ flags,
                                             void* __restrict__ d_out, size_t emb_base,
                                             float* __restrict__ B_ws, int n) {
    bool f32m = flags[0] > 0.5f;
    int wvid = (blockIdx.x * 256 + threadIdx.x) >> 6;   // global wave id
    int lane = threadIdx.x & 63;
    int grp = lane >> 4;      // 0..3: which row of the quad this lane reads
    int col4 = lane & 15;     // float4 column group: cols col4*4 .. col4*4+3
    int v0 = wvid * 2;
    int v1 = v0 + 1;
    if (v0 >= n) return;
    bool has1 = (v1 < n);

    // bias for this lane's column group (wave-uniform-ish, L2-resident)
    float4 bias4;
    if (f32m) {
        bias4 = ((const float4*)bias)[col4];
    } else {
        const bf16* bp = (const bf16*)bias + col4 * 4;
        bias4.x = __bfloat162float(bp[0]); bias4.y = __bfloat162float(bp[1]);
        bias4.z = __bfloat162float(bp[2]); bias4.w = __bfloat162float(bp[3]);
    }

    float dvA = dinv[v0];
    float dvB = has1 ? dinv[v1] : 0.0f;
    int e0a = rowptr[v0], e1a = rowptr[v0 + 1];
    int e0b = has1 ? rowptr[v1] : 0;
    int e1b = has1 ? rowptr[v1 + 1] : 0;
    int degA = e1a - e0a + 1;                 // +1: self row as item 0
    int degB = has1 ? (e1b - e0b + 1) : 0;
    int degMax = degA > degB ? degA : degB;

    float4 accA = {0, 0, 0, 0}, accB = {0, 0, 0, 0};

    for (int base = 0; base < degMax; base += 64) {
        // coalesced src-id loads for this 64-item chunk (item 0 = self)
        int jA = base + lane;
        int sA_l = -1;
        if (jA == 0) sA_l = v0;
        else if (jA < degA) sA_l = srcs[e0a + jA - 1];
        int sB_l = -1;
        if (has1) {
            int jB = base + lane;
            if (jB == 0) sB_l = v1;
            else if (jB < degB) sB_l = srcs[e0b + jB - 1];
        }
        int rem = degMax - base;
        int mq = rem < 64 ? rem : 64;

        for (int q = 0; q < mq; q += 16) {
            int sa[4], sb[4];
#pragma unroll
            for (int u = 0; u < 4; ++u) {
                int idx = q + 4 * u + grp;          // < 64 always
                sa[u] = __shfl(sA_l, idx, 64);
                sb[u] = __shfl(sB_l, idx, 64);
            }
            float4 va[4], vb[4];
#pragma unroll
            for (int u = 0; u < 4; ++u) {
                va[u] = make_float4(0, 0, 0, 0);
                if (sa[u] >= 0)
                    va[u] = *((const float4*)(t + ((size_t)sa[u] << 6)) + col4);
                vb[u] = make_float4(0, 0, 0, 0);
                if (sb[u] >= 0)
                    vb[u] = *((const float4*)(t + ((size_t)sb[u] << 6)) + col4);
            }
#pragma unroll
            for (int u = 0; u < 4; ++u) {
                accA.x += va[u].x; accA.y += va[u].y; accA.z += va[u].z; accA.w += va[u].w;
                accB.x += vb[u].x; accB.y += vb[u].y; accB.z += vb[u].z; accB.w += vb[u].w;
            }
        }
    }

    // butterfly across the 4 lane-groups (lanes l, l^16, l^32, l^48)
#pragma unroll
    for (int off = 16; off < 64; off <<= 1) {
        accA.x += __shfl_xor(accA.x, off, 64);
        accA.y += __shfl_xor(accA.y, off, 64);
        accA.z += __shfl_xor(accA.z, off, 64);
        accA.w += __shfl_xor(accA.w, off, 64);
        accB.x += __shfl_xor(accB.x, off, 64);
        accB.y += __shfl_xor(accB.y, off, 64);
        accB.z += __shfl_xor(accB.z, off, 64);
        accB.w += __shfl_xor(accB.w, off, 64);
    }

    // epilogue: grp 0 stores node A, grp 1 stores node B (sums replicated)
    int v = -1; float4 acc; float dv = 0.0f;
    if (grp == 0) { v = v0; acc = accA; dv = dvA; }
    else if (grp == 1 && has1) { v = v1; acc = accB; dv = dvB; }
    if (v >= 0) {
        acc.x = acc.x * dv + bias4.x;
        acc.y = acc.y * dv + bias4.y;
        acc.z = acc.z * dv + bias4.z;
        acc.w = acc.w * dv + bias4.w;
        if (EP == 0) {
            acc.x = fmaxf(acc.x, 0.0f); acc.y = fmaxf(acc.y, 0.0f);
            acc.z = fmaxf(acc.z, 0.0f); acc.w = fmaxf(acc.w, 0.0f);
        }
        size_t ob = (size_t)v * 64 + col4 * 4;
        if (f32m) {
            *(float4*)((float*)d_out + emb_base + ob) = acc;
        } else {
            *(float4*)&B_ws[ob] = acc;
            if (EP == 1) {
                __hip_bfloat162 h0, h1;
                h0.x = __float2bfloat16(acc.x); h0.y = __float2bfloat16(acc.y);
                h1.x = __float2bfloat16(acc.z); h1.y = __float2bfloat16(acc.w);
                __hip_bfloat162* p = (__hip_bfloat162*)((bf16*)d_out + emb_base + ob);
                p[0] = h0; p[1] = h1;
            }
        }
    }
}

// ---------------- classifier: one thread per node, logits in registers ----------------

__device__ __forceinline__ void store_row40(void* out, size_t base, const float* a, bool f32m) {
    if (f32m) {
        float4* p = (float4*)((float*)out + base);
#pragma unroll
        for (int q = 0; q < 10; ++q) {
            float4 st = {a[q * 4 + 0], a[q * 4 + 1], a[q * 4 + 2], a[q * 4 + 3]};
            p[q] = st;
        }
    } else {
        __hip_bfloat162* p = (__hip_bfloat162*)((bf16*)out + base);
#pragma unroll
        for (int i = 0; i < 20; ++i) {
            __hip_bfloat162 h;
            h.x = __float2bfloat16(a[2 * i]);
            h.y = __float2bfloat16(a[2 * i + 1]);
            p[i] = h;
        }
    }
}

__global__ __launch_bounds__(256) void k_classifier(const float* __restrict__ flags,
                                                    const void* __restrict__ Wc,
                                                    const void* __restrict__ bc,
                                                    void* __restrict__ out,
                                                    size_t emb_base, size_t soft_base,
                                                    size_t hard_base,
                                                    const float* __restrict__ B_ws,
                                                    int n) {
    __shared__ __align__(16) float wcs[64 * 40];
    __shared__ __align__(16) float bcs[40];
    bool f32m = flags[0] > 0.5f;
    const float* emb = f32m ? ((const float*)out + emb_base) : B_ws;
    int tid = threadIdx.x;

    if (f32m) {
        for (int i = tid * 4; i < 64 * 40; i += 1024)
            *(float4*)&wcs[i] = *(const float4*)((const float*)Wc + i);
    } else {
        for (int i = tid; i < 64 * 40; i += 256)
            wcs[i] = __bfloat162float(((const bf16*)Wc)[i]);
    }
    if (tid < 40) bcs[tid] = loadf(bc, tid, f32m);
    __syncthreads();

    int node = blockIdx.x * 256 + tid;
    if (node >= n) return;

    float acc[40];
#pragma unroll
    for (int q = 0; q < 10; ++q) {
        float4 b4 = *(const float4*)&bcs[q * 4];
        acc[q * 4 + 0] = b4.x; acc[q * 4 + 1] = b4.y;
        acc[q * 4 + 2] = b4.z; acc[q * 4 + 3] = b4.w;
    }

    const float4* erow = (const float4*)(emb + (size_t)node * 64);
#pragma unroll 2
    for (int j = 0; j < 16; ++j) {
        float4 e4 = erow[j];
        float ev[4] = {e4.x, e4.y, e4.z, e4.w};
#pragma unroll
        for (int kk = 0; kk < 4; ++kk) {
            float e = ev[kk];
            const float4* wr = (const float4*)&wcs[(j * 4 + kk) * 40];
#pragma unroll
            for (int q = 0; q < 10; ++q) {
                float4 w = wr[q];                       // wave-uniform LDS broadcast
                acc[q * 4 + 0] = fmaf(e, w.x, acc[q * 4 + 0]);
                acc[q * 4 + 1] = fmaf(e, w.y, acc[q * 4 + 1]);
                acc[q * 4 + 2] = fmaf(e, w.z, acc[q * 4 + 2]);
                acc[q * 4 + 3] = fmaf(e, w.w, acc[q * 4 + 3]);
            }
        }
    }

    // logits
    store_row40(out, (size_t)node * 40, acc, f32m);

    // max (tree)
    float m0 = acc[0], m1 = acc[1], m2 = acc[2], m3 = acc[3];
#pragma unroll
    for (int q = 1; q < 10; ++q) {
        m0 = fmaxf(m0, acc[q * 4 + 0]); m1 = fmaxf(m1, acc[q * 4 + 1]);
        m2 = fmaxf(m2, acc[q * 4 + 2]); m3 = fmaxf(m3, acc[q * 4 + 3]);
    }
    float m = fmaxf(fmaxf(m0, m1), fmaxf(m2, m3));

    // argmax: first index equal to max (matches jnp.argmax first-occurrence)
    int bi = 63;
#pragma unroll
    for (int c = 0; c < 40; ++c)
        if (acc[c] == m && c < bi) bi = c;

    // exp + sum
    float s = 0.0f;
#pragma unroll
    for (int c = 0; c < 40; ++c) {
        float e = expf(acc[c] - m);
        acc[c] = e;
        s += e;
    }
    float rs = 1.0f / s;
#pragma unroll
    for (int c = 0; c < 40; ++c) acc[c] *= rs;

    store_row40(out, soft_base + (size_t)node * 40, acc, f32m);
    storef(out, hard_base + node, (float)bi, f32m);
}

extern "C" void kernel_launch(void* const* d_in, const int* in_sizes, int n_in,
                              void* d_out, int out_size, void* d_ws, size_t ws_size,
                              hipStream_t stream) {
    const void* x  = d_in[0];
    const int*  ei = (const int*)d_in[1];
    const void* W1 = d_in[2];
    const void* b1 = d_in[3];
    const void* W2 = d_in[4];
    const void* b2 = d_in[5];
    const void* Wc = d_in[6];
    const void* bc = d_in[7];

    const int n = in_sizes[0] / 128;   // 100000
    const int E = in_sizes[1] / 2;     // 1200000
    const int NB = (n + 255) / 256;    // 391 buckets (<= 512)

    float* ws    = (float*)d_ws;
    const size_t npad = (((size_t)n + 1023) / 1024) * 1024;
    const size_t Epad = (((size_t)E + 255) / 256) * 256;
    float* flags  = ws;                         // 256
    int*   bcnt   = (int*)(ws + 256);           // 512
    int*   bbase  = (int*)(ws + 768);           // 768 (NB+1 used)
    int*   bcur   = (int*)(ws + 1536);          // 512
    int*   rowptr = (int*)(ws + 2048);          // npad (n+1 used)
    float* dinv   = (float*)(rowptr + npad);    // npad
    int*   srcs   = (int*)(dinv + npad);        // Epad
    float* A      = (float*)(srcs + Epad);      // n*64 f32 (scaled gemm outputs)
    float* B_ws   = A + (size_t)n * 64;         // n*64 f32 (only if !f32m)
    int2*  recs   = (int2*)B_ws;                // E records, aliases B_ws (dead before use)

    const size_t emb_base  = (size_t)n * 40;
    const size_t soft_base = (size_t)n * 104;
    const size_t hard_base = (size_t)n * 144;
    float* h1_f32m = (float*)d_out + emb_base;  // h1 scratch in emb region (f32m)

    const int gS  = (E + 256 * SCB_EPT - 1) / (256 * SCB_EPT);  // hist/scatter blocks
    const int gG  = (n + 63) / 64;
    const int gW  = (n + 7) / 8;                // 2 nodes/wave, 4 waves/block
    const int gC  = (n + 255) / 256;

    k_detect<<<1, 64, 0, stream>>>(x, ei, flags);

    // CSR build via 2-level counting sort
    k_zero_small<<<2, 256, 0, stream>>>(bcnt, 512);
    k_bucket_hist<<<gS, 256, 0, stream>>>(ei, flags, bcnt, E, NB);
    k_scan_buckets<<<1, 512, 0, stream>>>(bcnt, bbase, bcur, NB);
    k_bucket_scatter<<<gS, 256, 0, stream>>>(ei, flags, bcur, recs, E, NB);
    k_bucket_csr<<<NB, 256, 0, stream>>>(recs, bbase, rowptr, dinv, srcs, n, E);

    // conv1: A = (x @ W1)*dinv  — MFMA for bf16 mode, VALU kernel for f32 mode
    k_gemm_mfma1<<<gG, 256, 0, stream>>>(x, W1, flags, dinv, A, n);
    k_gemm3<128, false, true><<<gG, 256, 0, stream>>>(x, x, W1, flags, dinv, A, n);
    k_agg<0><<<gW, 256, 0, stream>>>(A, dinv, rowptr, srcs, b1, flags,
                                     d_out, emb_base, B_ws, n);

    // conv2: A = (h1 @ W2)*dinv ; fused agg + b2 -> final embedding
    k_gemm3<64, true, false><<<gG, 256, 0, stream>>>(h1_f32m, B_ws, W2, flags, dinv, A, n);
    k_agg<1><<<gW, 256, 0, stream>>>(A, dinv, rowptr, srcs, b2, flags,
                                     d_out, emb_base, B_ws, n);

    // classifier + softmax + argmax
    k_classifier<<<gC, 256, 0, stream>>>(flags, Wc, bc, d_out,
                                         emb_base, soft_base, hard_base, B_ws, n);
}

// Round 5
// 313.057 us; speedup vs baseline: 1.0510x; 1.0510x over previous
//
#include <hip/hip_runtime.h>
#include <hip/hip_bf16.h>
#include <math.h>

typedef __hip_bfloat16 bf16;
typedef __attribute__((ext_vector_type(8))) short bf16x8;
typedef __attribute__((ext_vector_type(4))) float f32x4;

// ---------------- dtype-flexible accessors ----------------
__device__ __forceinline__ float loadf(const void* p, size_t i, bool f32m) {
    return f32m ? ((const float*)p)[i]
                : __bfloat162float(((const bf16*)p)[i]);
}
__device__ __forceinline__ void storef(void* p, size_t i, float v, bool f32m) {
    if (f32m) ((float*)p)[i] = v;
    else      ((bf16*)p)[i] = __float2bfloat16(v);
}
// row 0 = src, row 1 = dst; e64 => int64 buffer, read low word
__device__ __forceinline__ int ldidx(const int* w, size_t e, bool e64, size_t E, int row) {
    return e64 ? w[2 * (row * E + e)] : w[row * E + e];
}

// f32 <-> bf16-bits helpers (RNE), branch-free
__device__ __forceinline__ unsigned short f2bf(float f) {
    unsigned u = __float_as_uint(f);
    unsigned r = (u + 0x7FFFu + ((u >> 16) & 1u)) >> 16;
    return (unsigned short)r;
}
__device__ __forceinline__ float bf2f(unsigned short h) {
    return __uint_as_float(((unsigned)h) << 16);
}

// ---------------- dtype detection (one wave) ----------------
__global__ void k_detect(const void* x, const int* ei, float* flags) {
    int lane = threadIdx.x;
    const unsigned short* hx = (const unsigned short*)x;
    unsigned short u = hx[2 * lane];
    int ex = (u >> 7) & 0xFF;
    bool tame = (ex >= 117 && ex <= 136);
    unsigned long long mt = __ballot(tame);
    unsigned long long mz = __ballot(ei[2 * lane + 1] != 0);
    if (lane == 0) {
        flags[0] = (__popcll(mt) >= 48) ? 0.0f : 1.0f;  // 1 => f32 inputs
        flags[1] = (mz == 0ULL) ? 1.0f : 0.0f;          // 1 => int64 edge_index
    }
}

// ---------------- CSR build: 2-level counting sort ----------------
// bucket = dst >> 8 (256 nodes per bucket), NB = ceil(n/256) <= 512

__global__ void k_zero_small(int* __restrict__ p, int m) {
    int i = blockIdx.x * 256 + threadIdx.x;
    if (i < m) p[i] = 0;
}

#define SCB_EPT 16   // edges per thread in hist/scatter (4096 per block)

__global__ __launch_bounds__(256) void k_bucket_hist(const int* __restrict__ ei,
                                                     const float* __restrict__ flags,
                                                     int* __restrict__ bcnt, int E, int NB) {
    __shared__ int lcnt[512];
    bool e64 = flags[1] > 0.5f;
    int tid = threadIdx.x;
    for (int i = tid; i < NB; i += 256) lcnt[i] = 0;
    __syncthreads();
    int base = blockIdx.x * 256 * SCB_EPT;
#pragma unroll
    for (int j = 0; j < SCB_EPT; ++j) {
        int e = base + j * 256 + tid;
        if (e < E) atomicAdd(&lcnt[ldidx(ei, e, e64, E, 1) >> 8], 1);
    }
    __syncthreads();
    for (int i = tid; i < NB; i += 256) {
        int c = lcnt[i];
        if (c) atomicAdd(&bcnt[i], c);
    }
}

// single block of 512: scan bcnt -> bbase (exclusive, NB+1), bcur copy
__global__ __launch_bounds__(512) void k_scan_buckets(const int* __restrict__ bcnt,
                                                      int* __restrict__ bbase,
                                                      int* __restrict__ bcur, int NB) {
    __shared__ int sh[512];
    int tid = threadIdx.x;
    int v = (tid < NB) ? bcnt[tid] : 0;
    sh[tid] = v;
    __syncthreads();
    for (int off = 1; off < 512; off <<= 1) {
        int t = (tid >= off) ? sh[tid - off] : 0;
        __syncthreads();
        sh[tid] += t;
        __syncthreads();
    }
    if (tid < NB) {
        int ex = sh[tid] - v;
        bbase[tid] = ex;
        bcur[tid] = ex;
    }
    if (tid == 0) bbase[NB] = sh[511];
}

// scatter (src,dst) records into bucket regions; per-block LDS rank ->
// consecutive positions per (block,bucket) -> near-sequential writes
__global__ __launch_bounds__(256) void k_bucket_scatter(const int* __restrict__ ei,
                                                        const float* __restrict__ flags,
                                                        int* __restrict__ bcur,
                                                        int2* __restrict__ recs,
                                                        int E, int NB) {
    __shared__ int lcnt[512], lrank[512], lbase[512];
    bool e64 = flags[1] > 0.5f;
    int tid = threadIdx.x;
    for (int i = tid; i < NB; i += 256) { lcnt[i] = 0; lrank[i] = 0; }
    __syncthreads();
    int base = blockIdx.x * 256 * SCB_EPT;
    int s[SCB_EPT], d[SCB_EPT];
#pragma unroll
    for (int j = 0; j < SCB_EPT; ++j) {
        int e = base + j * 256 + tid;
        if (e < E) {
            s[j] = ldidx(ei, e, e64, E, 0);
            d[j] = ldidx(ei, e, e64, E, 1);
            atomicAdd(&lcnt[d[j] >> 8], 1);
        } else d[j] = -1;
    }
    __syncthreads();
    for (int i = tid; i < NB; i += 256) {
        int c = lcnt[i];
        lbase[i] = c ? atomicAdd(&bcur[i], c) : 0;
    }
    __syncthreads();
#pragma unroll
    for (int j = 0; j < SCB_EPT; ++j) {
        if (d[j] >= 0) {
            int b = d[j] >> 8;
            int r = atomicAdd(&lrank[b], 1);
            recs[lbase[b] + r] = make_int2(s[j], d[j]);
        }
    }
}

// one block per bucket: node counts + scan -> rowptr, dinv; then scatter srcs
// into the bucket's contiguous range (L2-local full-line writes)
__global__ __launch_bounds__(256) void k_bucket_csr(const int2* __restrict__ recs,
                                                    const int* __restrict__ bbase,
                                                    int* __restrict__ rowptr,
                                                    float* __restrict__ dinv,
                                                    int* __restrict__ srcs,
                                                    int n, int E) {
    __shared__ int lcnt[256];
    __shared__ int lcur[256];
    int b = blockIdx.x, tid = threadIdx.x;
    int e0 = bbase[b], e1 = bbase[b + 1];
    lcnt[tid] = 0;
    __syncthreads();
    for (int i = e0 + tid; i < e1; i += 256)
        atomicAdd(&lcnt[recs[i].y & 255], 1);
    __syncthreads();
    int c = lcnt[tid];
    lcur[tid] = c;
    __syncthreads();
    for (int off = 1; off < 256; off <<= 1) {
        int t = (tid >= off) ? lcur[tid - off] : 0;
        __syncthreads();
        lcur[tid] += t;
        __syncthreads();
    }
    int rp = bbase[b] + lcur[tid] - c;   // exclusive
    int node = (b << 8) + tid;
    if (node < n) {
        rowptr[node] = rp;
        dinv[node] = rsqrtf((float)(c + 1));
    }
    lcur[tid] = rp;
    __syncthreads();
    for (int i = e0 + tid; i < e1; i += 256) {
        int2 r = recs[i];
        int pos = atomicAdd(&lcur[r.y & 255], 1);
        srcs[pos] = r.x;
    }
    if (b == 0 && tid == 0) rowptr[n] = E;
}

// ---------------- MFMA dense transform (both modes): A = (X @ W)*rowscale ----------------
// f32 data path uses split-bf16 (hi+lo) with 3 MFMAs per product tile:
//   x*w ~= xh*wh + xh*wl + xl*wh      (drops xl*wl, ~2^-16 relative)
// bf16 data degenerates to lo==0. 4 waves/block, 64 rows x 64 cols per block.
// A-fragments straight from global (lane m=lane&15 row, k=(lane>>4)*8);
// W^T split-staged in LDS [64][K+8] bf16-bits (stride => 2-way banks = free).
template <int K, bool XALWAYSF32>
__global__ __launch_bounds__(256) void k_gconv_mfma(const void* __restrict__ Xa,
                                                    const void* __restrict__ Xb,
                                                    const void* __restrict__ W,
                                                    const float* __restrict__ flags,
                                                    const float* __restrict__ rowscale,
                                                    float* __restrict__ out, int n) {
    constexpr int KP = K + 8;
    __shared__ __align__(16) unsigned short wh[64 * KP];
    __shared__ __align__(16) unsigned short wlo[64 * KP];
    bool f32m = flags[0] > 0.5f;
    const void* X = f32m ? Xa : Xb;
    bool xf32 = XALWAYSF32 || f32m;
    int tid = threadIdx.x;

    // stage W^T split into hi/lo bf16 bits
    if (f32m) {
        for (int i = tid * 4; i < K * 64; i += 1024) {
            int k = i >> 6, c = i & 63;
            float4 v = *(const float4*)((const float*)W + i);
            float vv[4] = {v.x, v.y, v.z, v.w};
#pragma unroll
            for (int q = 0; q < 4; ++q) {
                unsigned short h = f2bf(vv[q]);
                unsigned short l = f2bf(vv[q] - bf2f(h));
                wh [(c + q) * KP + k] = h;
                wlo[(c + q) * KP + k] = l;
            }
        }
    } else {
        for (int i = tid; i < K * 64; i += 256) {
            int k = i >> 6, c = i & 63;
            wh [c * KP + k] = ((const unsigned short*)W)[i];
            wlo[c * KP + k] = 0;
        }
    }
    __syncthreads();

    int lane = tid & 63, wv = tid >> 6;
    int r0 = blockIdx.x * 64 + wv * 16;
    int mrow = lane & 15, kgrp = lane >> 4;
    int row = r0 + mrow;
    bool rok = (row < n);

    f32x4 acc[4];
#pragma unroll
    for (int ct = 0; ct < 4; ++ct) acc[ct] = (f32x4){0.0f, 0.0f, 0.0f, 0.0f};

    const float*          xrf = (const float*)X          + (size_t)(rok ? row : 0) * K;
    const unsigned short* xrb = (const unsigned short*)X + (size_t)(rok ? row : 0) * K;

#pragma unroll
    for (int ks = 0; ks < K / 32; ++ks) {
        int kb = ks * 32 + kgrp * 8;
        bf16x8 ahi = {0, 0, 0, 0, 0, 0, 0, 0};
        bf16x8 alo = {0, 0, 0, 0, 0, 0, 0, 0};
        if (rok) {
            if (xf32) {
                float4 v0 = *(const float4*)(xrf + kb);
                float4 v1 = *(const float4*)(xrf + kb + 4);
                float fv[8] = {v0.x, v0.y, v0.z, v0.w, v1.x, v1.y, v1.z, v1.w};
#pragma unroll
                for (int j = 0; j < 8; ++j) {
                    unsigned short h = f2bf(fv[j]);
                    ahi[j] = (short)h;
                    alo[j] = (short)f2bf(fv[j] - bf2f(h));
                }
            } else {
                ahi = *(const bf16x8*)(xrb + kb);   // alo stays 0
            }
        }
#pragma unroll
        for (int ct = 0; ct < 4; ++ct) {
            int c = ct * 16 + mrow;
            bf16x8 bhi = *(const bf16x8*)&wh [c * KP + kb];
            bf16x8 blo = *(const bf16x8*)&wlo[c * KP + kb];
            acc[ct] = __builtin_amdgcn_mfma_f32_16x16x32_bf16(ahi, bhi, acc[ct], 0, 0, 0);
            acc[ct] = __builtin_amdgcn_mfma_f32_16x16x32_bf16(ahi, blo, acc[ct], 0, 0, 0);
            acc[ct] = __builtin_amdgcn_mfma_f32_16x16x32_bf16(alo, bhi, acc[ct], 0, 0, 0);
        }
    }

    // C/D: col = ct*16 + (lane&15), row(within tile) = kgrp*4 + reg
    float sc[4];
    int obase = r0 + kgrp * 4;
#pragma unroll
    for (int r = 0; r < 4; ++r)
        sc[r] = (obase + r < n) ? rowscale[obase + r] : 0.0f;
#pragma unroll
    for (int ct = 0; ct < 4; ++ct) {
#pragma unroll
        for (int r = 0; r < 4; ++r) {
            int orow = obase + r;
            if (orow < n)
                out[(size_t)orow * 64 + ct * 16 + mrow] = acc[ct][r] * sc[r];
        }
    }
}

// ---------------- fused aggregation: 2 nodes per wave, dwordx4 gathers ----------------
// t = A_scaled (rows pre-multiplied by dinv[src]); result = dv*(t[v] + sum t[s]) + bias
template <int EP>
__global__ __launch_bounds__(256) void k_agg(const float* __restrict__ t,
                                             const float* __restrict__ dinv,
                                             const int* __restrict__ rowptr,
                                             const int* __restrict__ srcs,
                                             const void* __restrict__ bias,
                                             const float* __restrict__ flags,
                                             void* __restrict__ d_out, size_t emb_base,
                                             float* __restrict__ B_ws, int n) {
    bool f32m = flags[0] > 0.5f;
    int wvid = (blockIdx.x * 256 + threadIdx.x) >> 6;   // global wave id
    int lane = threadIdx.x & 63;
    int grp = lane >> 4;      // 0..3: which row of the quad this lane reads
    int col4 = lane & 15;     // float4 column group: cols col4*4 .. col4*4+3
    int v0 = wvid * 2;
    int v1 = v0 + 1;
    if (v0 >= n) return;
    bool has1 = (v1 < n);

    // bias for this lane's column group (wave-uniform-ish, L2-resident)
    float4 bias4;
    if (f32m) {
        bias4 = ((const float4*)bias)[col4];
    } else {
        const bf16* bp = (const bf16*)bias + col4 * 4;
        bias4.x = __bfloat162float(bp[0]); bias4.y = __bfloat162float(bp[1]);
        bias4.z = __bfloat162float(bp[2]); bias4.w = __bfloat162float(bp[3]);
    }

    float dvA = dinv[v0];
    float dvB = has1 ? dinv[v1] : 0.0f;
    int e0a = rowptr[v0], e1a = rowptr[v0 + 1];
    int e0b = has1 ? rowptr[v1] : 0;
    int e1b = has1 ? rowptr[v1 + 1] : 0;
    int degA = e1a - e0a + 1;                 // +1: self row as item 0
    int degB = has1 ? (e1b - e0b + 1) : 0;
    int degMax = degA > degB ? degA : degB;

    float4 accA = {0, 0, 0, 0}, accB = {0, 0, 0, 0};

    for (int base = 0; base < degMax; base += 64) {
        // coalesced src-id loads for this 64-item chunk (item 0 = self)
        int jA = base + lane;
        int sA_l = -1;
        if (jA == 0) sA_l = v0;
        else if (jA < degA) sA_l = srcs[e0a + jA - 1];
        int sB_l = -1;
        if (has1) {
            int jB = base + lane;
            if (jB == 0) sB_l = v1;
            else if (jB < degB) sB_l = srcs[e0b + jB - 1];
        }
        int rem = degMax - base;
        int mq = rem < 64 ? rem : 64;

        for (int q = 0; q < mq; q += 16) {
            int sa[4], sb[4];
#pragma unroll
            for (int u = 0; u < 4; ++u) {
                int idx = q + 4 * u + grp;          // < 64 always
                sa[u] = __shfl(sA_l, idx, 64);
                sb[u] = __shfl(sB_l, idx, 64);
            }
            float4 va[4], vb[4];
#pragma unroll
            for (int u = 0; u < 4; ++u) {
                va[u] = make_float4(0, 0, 0, 0);
                if (sa[u] >= 0)
                    va[u] = *((const float4*)(t + ((size_t)sa[u] << 6)) + col4);
                vb[u] = make_float4(0, 0, 0, 0);
                if (sb[u] >= 0)
                    vb[u] = *((const float4*)(t + ((size_t)sb[u] << 6)) + col4);
            }
#pragma unroll
            for (int u = 0; u < 4; ++u) {
                accA.x += va[u].x; accA.y += va[u].y; accA.z += va[u].z; accA.w += va[u].w;
                accB.x += vb[u].x; accB.y += vb[u].y; accB.z += vb[u].z; accB.w += vb[u].w;
            }
        }
    }

    // butterfly across the 4 lane-groups (lanes l, l^16, l^32, l^48)
#pragma unroll
    for (int off = 16; off < 64; off <<= 1) {
        accA.x += __shfl_xor(accA.x, off, 64);
        accA.y += __shfl_xor(accA.y, off, 64);
        accA.z += __shfl_xor(accA.z, off, 64);
        accA.w += __shfl_xor(accA.w, off, 64);
        accB.x += __shfl_xor(accB.x, off, 64);
        accB.y += __shfl_xor(accB.y, off, 64);
        accB.z += __shfl_xor(accB.z, off, 64);
        accB.w += __shfl_xor(accB.w, off, 64);
    }

    // epilogue: grp 0 stores node A, grp 1 stores node B (sums replicated)
    int v = -1; float4 acc; float dv = 0.0f;
    if (grp == 0) { v = v0; acc = accA; dv = dvA; }
    else if (grp == 1 && has1) { v = v1; acc = accB; dv = dvB; }
    if (v >= 0) {
        acc.x = acc.x * dv + bias4.x;
        acc.y = acc.y * dv + bias4.y;
        acc.z = acc.z * dv + bias4.z;
        acc.w = acc.w * dv + bias4.w;
        if (EP == 0) {
            acc.x = fmaxf(acc.x, 0.0f); acc.y = fmaxf(acc.y, 0.0f);
            acc.z = fmaxf(acc.z, 0.0f); acc.w = fmaxf(acc.w, 0.0f);
        }
        size_t ob = (size_t)v * 64 + col4 * 4;
        if (f32m) {
            *(float4*)((float*)d_out + emb_base + ob) = acc;
        } else {
            *(float4*)&B_ws[ob] = acc;
            if (EP == 1) {
                __hip_bfloat162 h0, h1;
                h0.x = __float2bfloat16(acc.x); h0.y = __float2bfloat16(acc.y);
                h1.x = __float2bfloat16(acc.z); h1.y = __float2bfloat16(acc.w);
                __hip_bfloat162* p = (__hip_bfloat162*)((bf16*)d_out + emb_base + ob);
                p[0] = h0; p[1] = h1;
            }
        }
    }
}

// ---------------- classifier: one thread per node, logits in registers ----------------

__device__ __forceinline__ void store_row40(void* out, size_t base, const float* a, bool f32m) {
    if (f32m) {
        float4* p = (float4*)((float*)out + base);
#pragma unroll
        for (int q = 0; q < 10; ++q) {
            float4 st = {a[q * 4 + 0], a[q * 4 + 1], a[q * 4 + 2], a[q * 4 + 3]};
            p[q] = st;
        }
    } else {
        __hip_bfloat162* p = (__hip_bfloat162*)((bf16*)out + base);
#pragma unroll
        for (int i = 0; i < 20; ++i) {
            __hip_bfloat162 h;
            h.x = __float2bfloat16(a[2 * i]);
            h.y = __float2bfloat16(a[2 * i + 1]);
            p[i] = h;
        }
    }
}

__global__ __launch_bounds__(256) void k_classifier(const float* __restrict__ flags,
                                                    const void* __restrict__ Wc,
                                                    const void* __restrict__ bc,
                                                    void* __restrict__ out,
                                                    size_t emb_base, size_t soft_base,
                                                    size_t hard_base,
                                                    const float* __restrict__ B_ws,
                                                    int n) {
    __shared__ __align__(16) float wcs[64 * 40];
    __shared__ __align__(16) float bcs[40];
    bool f32m = flags[0] > 0.5f;
    const float* emb = f32m ? ((const float*)out + emb_base) : B_ws;
    int tid = threadIdx.x;

    if (f32m) {
        for (int i = tid * 4; i < 64 * 40; i += 1024)
            *(float4*)&wcs[i] = *(const float4*)((const float*)Wc + i);
    } else {
        for (int i = tid; i < 64 * 40; i += 256)
            wcs[i] = __bfloat162float(((const bf16*)Wc)[i]);
    }
    if (tid < 40) bcs[tid] = loadf(bc, tid, f32m);
    __syncthreads();

    int node = blockIdx.x * 256 + tid;
    if (node >= n) return;

    float acc[40];
#pragma unroll
    for (int q = 0; q < 10; ++q) {
        float4 b4 = *(const float4*)&bcs[q * 4];
        acc[q * 4 + 0] = b4.x; acc[q * 4 + 1] = b4.y;
        acc[q * 4 + 2] = b4.z; acc[q * 4 + 3] = b4.w;
    }

    const float4* erow = (const float4*)(emb + (size_t)node * 64);
#pragma unroll 2
    for (int j = 0; j < 16; ++j) {
        float4 e4 = erow[j];
        float ev[4] = {e4.x, e4.y, e4.z, e4.w};
#pragma unroll
        for (int kk = 0; kk < 4; ++kk) {
            float e = ev[kk];
            const float4* wr = (const float4*)&wcs[(j * 4 + kk) * 40];
#pragma unroll
            for (int q = 0; q < 10; ++q) {
                float4 w = wr[q];                       // wave-uniform LDS broadcast
                acc[q * 4 + 0] = fmaf(e, w.x, acc[q * 4 + 0]);
                acc[q * 4 + 1] = fmaf(e, w.y, acc[q * 4 + 1]);
                acc[q * 4 + 2] = fmaf(e, w.z, acc[q * 4 + 2]);
                acc[q * 4 + 3] = fmaf(e, w.w, acc[q * 4 + 3]);
            }
        }
    }

    // logits
    store_row40(out, (size_t)node * 40, acc, f32m);

    // max (tree)
    float m0 = acc[0], m1 = acc[1], m2 = acc[2], m3 = acc[3];
#pragma unroll
    for (int q = 1; q < 10; ++q) {
        m0 = fmaxf(m0, acc[q * 4 + 0]); m1 = fmaxf(m1, acc[q * 4 + 1]);
        m2 = fmaxf(m2, acc[q * 4 + 2]); m3 = fmaxf(m3, acc[q * 4 + 3]);
    }
    float m = fmaxf(fmaxf(m0, m1), fmaxf(m2, m3));

    // argmax: first index equal to max (matches jnp.argmax first-occurrence)
    int bi = 63;
#pragma unroll
    for (int c = 0; c < 40; ++c)
        if (acc[c] == m && c < bi) bi = c;

    // exp + sum
    float s = 0.0f;
#pragma unroll
    for (int c = 0; c < 40; ++c) {
        float e = expf(acc[c] - m);
        acc[c] = e;
        s += e;
    }
    float rs = 1.0f / s;
#pragma unroll
    for (int c = 0; c < 40; ++c) acc[c] *= rs;

    store_row40(out, soft_base + (size_t)node * 40, acc, f32m);
    storef(out, hard_base + node, (float)bi, f32m);
}

extern "C" void kernel_launch(void* const* d_in, const int* in_sizes, int n_in,
                              void* d_out, int out_size, void* d_ws, size_t ws_size,
                              hipStream_t stream) {
    const void* x  = d_in[0];
    const int*  ei = (const int*)d_in[1];
    const void* W1 = d_in[2];
    const void* b1 = d_in[3];
    const void* W2 = d_in[4];
    const void* b2 = d_in[5];
    const void* Wc = d_in[6];
    const void* bc = d_in[7];

    const int n = in_sizes[0] / 128;   // 100000
    const int E = in_sizes[1] / 2;     // 1200000
    const int NB = (n + 255) / 256;    // 391 buckets (<= 512)

    float* ws    = (float*)d_ws;
    const size_t npad = (((size_t)n + 1023) / 1024) * 1024;
    const size_t Epad = (((size_t)E + 255) / 256) * 256;
    float* flags  = ws;                         // 256
    int*   bcnt   = (int*)(ws + 256);           // 512
    int*   bbase  = (int*)(ws + 768);           // 768 (NB+1 used)
    int*   bcur   = (int*)(ws + 1536);          // 512
    int*   rowptr = (int*)(ws + 2048);          // npad (n+1 used)
    float* dinv   = (float*)(rowptr + npad);    // npad
    int*   srcs   = (int*)(dinv + npad);        // Epad
    float* A      = (float*)(srcs + Epad);      // n*64 f32 (scaled gemm outputs)
    float* B_ws   = A + (size_t)n * 64;         // n*64 f32 (only if !f32m)
    int2*  recs   = (int2*)B_ws;                // E records, aliases B_ws (dead before use)

    const size_t emb_base  = (size_t)n * 40;
    const size_t soft_base = (size_t)n * 104;
    const size_t hard_base = (size_t)n * 144;
    float* h1_f32m = (float*)d_out + emb_base;  // h1 scratch in emb region (f32m)

    const int gS  = (E + 256 * SCB_EPT - 1) / (256 * SCB_EPT);  // hist/scatter blocks
    const int gG  = (n + 63) / 64;
    const int gW  = (n + 7) / 8;                // 2 nodes/wave, 4 waves/block
    const int gC  = (n + 255) / 256;

    k_detect<<<1, 64, 0, stream>>>(x, ei, flags);

    // CSR build via 2-level counting sort
    k_zero_small<<<2, 256, 0, stream>>>(bcnt, 512);
    k_bucket_hist<<<gS, 256, 0, stream>>>(ei, flags, bcnt, E, NB);
    k_scan_buckets<<<1, 512, 0, stream>>>(bcnt, bbase, bcur, NB);
    k_bucket_scatter<<<gS, 256, 0, stream>>>(ei, flags, bcur, recs, E, NB);
    k_bucket_csr<<<NB, 256, 0, stream>>>(recs, bbase, rowptr, dinv, srcs, n, E);

    // conv1: A = (x @ W1)*dinv  — split-bf16 MFMA (f32 mode) / plain MFMA (bf16 mode)
    k_gconv_mfma<128, false><<<gG, 256, 0, stream>>>(x, x, W1, flags, dinv, A, n);
    k_agg<0><<<gW, 256, 0, stream>>>(A, dinv, rowptr, srcs, b1, flags,
                                     d_out, emb_base, B_ws, n);

    // conv2: A = (h1 @ W2)*dinv ; h1 is f32 in both modes
    k_gconv_mfma<64, true><<<gG, 256, 0, stream>>>(h1_f32m, B_ws, W2, flags, dinv, A, n);
    k_agg<1><<<gW, 256, 0, stream>>>(A, dinv, rowptr, srcs, b2, flags,
                                     d_out, emb_base, B_ws, n);

    // classifier + softmax + argmax
    k_classifier<<<gC, 256, 0, stream>>>(flags, Wc, bc, d_out,
                                         emb_base, soft_base, hard_base, B_ws, n);
}